// Round 1
// baseline (479.439 us; speedup 1.0000x reference)
//
#include <hip/hip_runtime.h>
#include <hip/hip_bf16.h>
#include <cstdint>

typedef __bf16 bf16x8 __attribute__((ext_vector_type(8)));
typedef float f32x4 __attribute__((ext_vector_type(4)));

__device__ inline unsigned short f2bf(float f) {
    union { float f; unsigned int u; } v; v.f = f;
    unsigned int u = v.u;
    unsigned int r = (u + 0x7FFFu + ((u >> 16) & 1u)) >> 16;
    return (unsigned short)r;
}

__device__ inline f32x4 mfma16(bf16x8 a, bf16x8 b, f32x4 c) {
    return __builtin_amdgcn_mfma_f32_16x16x32_bf16(a, b, c, 0, 0, 0);
}

__device__ inline bf16x8 ldfrag(const unsigned short* p) {
    uint4 v = *(const uint4*)p;
    return __builtin_bit_cast(bf16x8, v);
}

// ---------------- kernel 1: x fp32 -> bf16 ----------------
__global__ void k_convert_x(const float* __restrict__ in,
                            unsigned short* __restrict__ out, int n4) {
    int i = blockIdx.x * blockDim.x + threadIdx.x;
    if (i < n4) {
        float4 f = ((const float4*)in)[i];
        ushort4 o;
        o.x = f2bf(f.x); o.y = f2bf(f.y); o.z = f2bf(f.z); o.w = f2bf(f.w);
        ((ushort4*)out)[i] = o;
    }
}

// ---------------- kernel 2: W [1024][3072] fp32 -> Wt [3072][1024] bf16 ----
__global__ void k_transpose_w(const float* __restrict__ W,
                              unsigned short* __restrict__ Wt) {
    __shared__ float tile[32][33];
    int nt = blockIdx.x, kt = blockIdx.y;
    int tx = threadIdx.x & 31, ty = threadIdx.x >> 5;
#pragma unroll
    for (int yy = 0; yy < 4; ++yy) {
        int y = ty + yy * 8;
        tile[y][tx] = W[(size_t)(kt * 32 + y) * 3072 + nt * 32 + tx];
    }
    __syncthreads();
#pragma unroll
    for (int yy = 0; yy < 4; ++yy) {
        int nrow = ty + yy * 8;
        Wt[(size_t)(nt * 32 + nrow) * 1024 + kt * 32 + tx] = f2bf(tile[tx][nrow]);
    }
}

// ---------------- kernel 3: qkv = x @ W + b, bf16 MFMA GEMM ----------------
// A [8192][1024] bf16 row-major, Bt [3072][1024] bf16 row-major (B^T),
// C [8192][3072] bf16. 128x128 tile, BK=32, 4 waves, 4x4 16x16x32 MFMA each.
__global__ __launch_bounds__(256) void k_qkv_gemm(
    const unsigned short* __restrict__ A,
    const unsigned short* __restrict__ Bt,
    const float* __restrict__ bias,
    unsigned short* __restrict__ C) {
    __shared__ unsigned short As[128 * 32];
    __shared__ unsigned short Bs[128 * 32];
    const int tid = threadIdx.x;
    const int lane = tid & 63;
    const int w = tid >> 6;
    const int wm = w >> 1, wn = w & 1;
    const int l15 = lane & 15;
    const int quad = lane >> 4;
    const int m0 = blockIdx.y * 128;
    const int n0 = blockIdx.x * 128;

    f32x4 acc[4][4] = {};

    for (int k0 = 0; k0 < 1024; k0 += 32) {
#pragma unroll
        for (int i = 0; i < 2; ++i) {
            int c = tid + i * 256;
            int row = c >> 2, seg = c & 3;
            uint4 va = *(const uint4*)(A + (size_t)(m0 + row) * 1024 + k0 + seg * 8);
            *(uint4*)(As + row * 32 + seg * 8) = va;
            uint4 vb = *(const uint4*)(Bt + (size_t)(n0 + row) * 1024 + k0 + seg * 8);
            *(uint4*)(Bs + row * 32 + seg * 8) = vb;
        }
        __syncthreads();
        const int col8 = quad * 8;
        bf16x8 af[4], bfr[4];
#pragma unroll
        for (int i = 0; i < 4; ++i)
            af[i] = ldfrag(As + (wm * 64 + i * 16 + l15) * 32 + col8);
#pragma unroll
        for (int j = 0; j < 4; ++j)
            bfr[j] = ldfrag(Bs + (wn * 64 + j * 16 + l15) * 32 + col8);
#pragma unroll
        for (int i = 0; i < 4; ++i)
#pragma unroll
            for (int j = 0; j < 4; ++j)
                acc[i][j] = mfma16(af[i], bfr[j], acc[i][j]);
        __syncthreads();
    }
    // epilogue: C/D layout col=lane&15, row=quad*4+r
#pragma unroll
    for (int i = 0; i < 4; ++i) {
#pragma unroll
        for (int j = 0; j < 4; ++j) {
            int col = n0 + wn * 64 + j * 16 + l15;
            float bv = bias[col];
#pragma unroll
            for (int r = 0; r < 4; ++r) {
                int row = m0 + wm * 64 + i * 16 + quad * 4 + r;
                C[(size_t)row * 3072 + col] = f2bf(acc[i][j][r] + bv);
            }
        }
    }
}

// ---------------- kernel 4: causal flash attention ----------------
// qkv [B*S][3072] bf16, head h: Q@h*192, K@h*192+64, V@h*192+128.
// grid (32 qtiles, 16 heads, 4 batch), 256 threads, wave w owns q-rows w*16..+16.
__global__ __launch_bounds__(256) void k_attn(
    const unsigned short* __restrict__ qkv,
    float* __restrict__ out) {
    const int qt = blockIdx.x;
    const int h = blockIdx.y;
    const int b = blockIdx.z;
    const int tid = threadIdx.x;
    const int lane = tid & 63;
    const int w = tid >> 6;
    const int l15 = lane & 15;
    const int quad = lane >> 4;

    __shared__ unsigned short Qs[64][72];
    __shared__ unsigned short Ks[64][72];
    __shared__ unsigned short Vt[64][72];  // Vt[d][k ^ ((d>>3)<<3)]
    __shared__ unsigned short Ps[4][16][72];

    const size_t base = (size_t)b * 2048 * 3072;
    const int qoff = h * 192, koff = h * 192 + 64, voff = h * 192 + 128;

    // stage Q tile [64][64]
#pragma unroll
    for (int i = 0; i < 2; ++i) {
        int c = tid + i * 256;
        int row = c >> 3, seg = c & 7;
        uint4 v = *(const uint4*)(qkv + base + (size_t)(qt * 64 + row) * 3072 + qoff + seg * 8);
        *(uint4*)(&Qs[row][seg * 8]) = v;
    }

    f32x4 o[4] = {};
    float m_r[4], l_r[4];
#pragma unroll
    for (int r = 0; r < 4; ++r) { m_r[r] = -1e30f; l_r[r] = 0.f; }

    const float sc = 0.125f * 1.44269504088896340736f;  // 1/sqrt(64) * log2(e)

    for (int kt = 0; kt <= qt; ++kt) {
        __syncthreads();  // previous-iter consumers done (also orders Q staging)
        // stage K tile and transposed-swizzled V tile
#pragma unroll
        for (int i = 0; i < 2; ++i) {
            int c = tid + i * 256;
            int row = c >> 3, seg = c & 7;
            const size_t gro = base + (size_t)(kt * 64 + row) * 3072;
            uint4 kv = *(const uint4*)(qkv + gro + koff + seg * 8);
            *(uint4*)(&Ks[row][seg * 8]) = kv;
            uint4 vv = *(const uint4*)(qkv + gro + voff + seg * 8);
            unsigned int words[4] = {vv.x, vv.y, vv.z, vv.w};
#pragma unroll
            for (int u = 0; u < 4; ++u) {
                int d0 = seg * 8 + u * 2;
                int sw = (d0 >> 3) << 3;
                Vt[d0][row ^ sw] = (unsigned short)(words[u] & 0xFFFFu);
                Vt[d0 + 1][row ^ sw] = (unsigned short)(words[u] >> 16);
            }
        }
        __syncthreads();

        // S = Q K^T (this wave's 16 q-rows x 64 k-cols)
        bf16x8 aq0 = ldfrag(&Qs[w * 16 + l15][quad * 8]);
        bf16x8 aq1 = ldfrag(&Qs[w * 16 + l15][quad * 8 + 32]);
        f32x4 s[4];
#pragma unroll
        for (int j = 0; j < 4; ++j) {
            f32x4 z = {0.f, 0.f, 0.f, 0.f};
            z = mfma16(aq0, ldfrag(&Ks[j * 16 + l15][quad * 8]), z);
            z = mfma16(aq1, ldfrag(&Ks[j * 16 + l15][quad * 8 + 32]), z);
            s[j] = z;
        }

        // scale + causal mask + row max (C-layout: row=quad*4+r, col=l15)
        const bool diag = (kt == qt);
        const int qg0 = qt * 64 + w * 16 + quad * 4;
        float s2[4][4];
        float mloc[4] = {-1e30f, -1e30f, -1e30f, -1e30f};
#pragma unroll
        for (int j = 0; j < 4; ++j) {
            int kg = kt * 64 + j * 16 + l15;
#pragma unroll
            for (int r = 0; r < 4; ++r) {
                float v = s[j][r] * sc;
                if (diag && kg > qg0 + r) v = -1e30f;
                s2[j][r] = v;
                mloc[r] = fmaxf(mloc[r], v);
            }
        }
#pragma unroll
        for (int off = 8; off >= 1; off >>= 1)
#pragma unroll
            for (int r = 0; r < 4; ++r)
                mloc[r] = fmaxf(mloc[r], __shfl_xor(mloc[r], off, 64));

        float alpha[4], psum[4];
#pragma unroll
        for (int r = 0; r < 4; ++r) {
            float mn = fmaxf(m_r[r], mloc[r]);
            alpha[r] = exp2f(m_r[r] - mn);
            m_r[r] = mn;
            psum[r] = 0.f;
        }
        // P = exp2(s2 - m), write to per-wave LDS (C-layout -> A-layout)
#pragma unroll
        for (int j = 0; j < 4; ++j)
#pragma unroll
            for (int r = 0; r < 4; ++r) {
                float p = exp2f(s2[j][r] - m_r[r]);
                psum[r] += p;
                Ps[w][quad * 4 + r][j * 16 + l15] = f2bf(p);
            }
#pragma unroll
        for (int off = 8; off >= 1; off >>= 1)
#pragma unroll
            for (int r = 0; r < 4; ++r)
                psum[r] += __shfl_xor(psum[r], off, 64);
#pragma unroll
        for (int r = 0; r < 4; ++r)
            l_r[r] = l_r[r] * alpha[r] + psum[r];
#pragma unroll
        for (int jd = 0; jd < 4; ++jd)
#pragma unroll
            for (int r = 0; r < 4; ++r)
                o[jd][r] *= alpha[r];

        // O += P V  (A-frag from Ps, B-frag from swizzled Vt)
        bf16x8 ap0 = ldfrag(&Ps[w][l15][quad * 8]);
        bf16x8 ap1 = ldfrag(&Ps[w][l15][quad * 8 + 32]);
#pragma unroll
        for (int jd = 0; jd < 4; ++jd) {
            int n = jd * 16 + l15;
            int sw = (n >> 3) << 3;
            o[jd] = mfma16(ap0, ldfrag(&Vt[n][(quad * 8) ^ sw]), o[jd]);
            o[jd] = mfma16(ap1, ldfrag(&Vt[n][(quad * 8 + 32) ^ sw]), o[jd]);
        }
    }

    // epilogue: out[b][q][h*64 + d] fp32
    float inv[4];
#pragma unroll
    for (int r = 0; r < 4; ++r) inv[r] = 1.0f / l_r[r];
    const size_t obase = ((size_t)b * 2048 + qt * 64 + w * 16) * 1024 + h * 64;
#pragma unroll
    for (int jd = 0; jd < 4; ++jd)
#pragma unroll
        for (int r = 0; r < 4; ++r) {
            int row = quad * 4 + r;
            out[obase + (size_t)row * 1024 + jd * 16 + l15] = o[jd][r] * inv[r];
        }
}

extern "C" void kernel_launch(void* const* d_in, const int* in_sizes, int n_in,
                              void* d_out, int out_size, void* d_ws, size_t ws_size,
                              hipStream_t stream) {
    const float* x = (const float*)d_in[0];     // [4,2048,1024]
    const float* W = (const float*)d_in[1];     // [1024,3072]
    const float* bq = (const float*)d_in[2];    // [3072]
    float* out = (float*)d_out;                 // [4,2048,1024]

    unsigned short* xbf = (unsigned short*)d_ws;           // 8192*1024
    unsigned short* wtbf = xbf + (size_t)8192 * 1024;      // 3072*1024
    unsigned short* qkvbf = wtbf + (size_t)3072 * 1024;    // 8192*3072
    // total ws use: 73,400,320 bytes

    k_convert_x<<<8192, 256, 0, stream>>>(x, xbf, 8192 * 1024 / 4);
    k_transpose_w<<<dim3(96, 32), 256, 0, stream>>>(W, wtbf);
    k_qkv_gemm<<<dim3(24, 64), 256, 0, stream>>>(xbf, wtbf, bq, qkvbf);
    k_attn<<<dim3(32, 16, 4), 256, 0, stream>>>(qkvbf, out);
}